// Round 1
// baseline (100.388 us; speedup 1.0000x reference)
//
#include <hip/hip_runtime.h>
#include <stdint.h>

#define BATCH   2048
#define INDIM   512
#define OUTDIM  512
#define KP      4352      // padded K: 4096 data + 8 bias rows + 248 zeros = 68*64
#define NBLK_A  2048
#define NBLK_B  544       // 68 k-tiles * 8 n-tiles
#define SPLITK  4
#define KSTEPS  17        // 68 / SPLITK

typedef __attribute__((ext_vector_type(4))) float  f32x4;
typedef __attribute__((ext_vector_type(8))) __bf16 bf16x8;
typedef __attribute__((ext_vector_type(8))) unsigned short u16x8;
typedef __attribute__((ext_vector_type(4))) unsigned short u16x4;

__device__ __forceinline__ unsigned short f2bf(float x) {
  unsigned int u = __float_as_uint(x);
  u += 0x7fffu + ((u >> 16) & 1u);      // round-to-nearest-even
  return (unsigned short)(u >> 16);
}

__device__ __forceinline__ void llds16(const void* g, void* s) {
  __builtin_amdgcn_global_load_lds(
      (__attribute__((address_space(1))) void*)g,
      (__attribute__((address_space(3))) void*)s, 16, 0, 0);
}

// ---------------------------------------------------------------------------
// prep: blocks [0,2048) build bf16 A' rows; blocks [2048,2592) build bf16 B^T
// A'[b,k] = basis[b, k>>9] * feat[b, k&511]   (k <  4096)
//         = basis[b, k-4096]                  (k in [4096,4104))
//         = 0                                 (else)
// Bt[n,k] = W_flat[k*512+n] (k<4096) | b_wts[(k-4096)*512+n] (k<4104) | 0
// ---------------------------------------------------------------------------
__global__ __launch_bounds__(256) void prep_kernel(
    const float* __restrict__ inp, const float* __restrict__ W,
    const float* __restrict__ bwts, unsigned short* __restrict__ Abf,
    unsigned short* __restrict__ Btf) {
  const int tid = threadIdx.x;
  const int bx  = blockIdx.x;
  if (bx < NBLK_A) {
    const float* row = inp + (size_t)bx * (INDIM + 1);
    const float t = row[0];
    float bs[8];
    bs[0] = 1.0f; bs[1] = t; bs[2] = t * t; bs[3] = bs[2] * t;
    const float kn[4] = {0.2f, 0.4f, 0.6f, 0.8f};
#pragma unroll
    for (int c = 0; c < 4; ++c) {
      float d = fmaxf(t - kn[c], 0.0f);
      bs[4 + c] = d * d * d;
    }
    unsigned short* Arow = Abf + (size_t)bx * KP;
    for (int k4 = tid * 4; k4 < KP; k4 += 1024) {
      float v0, v1, v2, v3;
      if (k4 < 4096) {
        const float s = bs[k4 >> 9];       // 4|512 so all 4 share s
        const int i = k4 & 511;
        v0 = s * row[1 + i]; v1 = s * row[2 + i];
        v2 = s * row[3 + i]; v3 = s * row[4 + i];
      } else if (k4 < 4104) {
        const int s0 = k4 - 4096;          // k4 = 4096 or 4100
        v0 = bs[s0]; v1 = bs[s0 + 1]; v2 = bs[s0 + 2]; v3 = bs[s0 + 3];
      } else {
        v0 = v1 = v2 = v3 = 0.0f;
      }
      u16x4 o;
      o.x = f2bf(v0); o.y = f2bf(v1); o.z = f2bf(v2); o.w = f2bf(v3);
      *(u16x4*)&Arow[k4] = o;
    }
  } else {
    const int bb = bx - NBLK_A;            // 0..543
    const int kt = bb >> 3, ntile = bb & 7;
    const int k0 = kt * 64, n0 = ntile * 64;
    __shared__ float Ts[64][65];           // [n_local][k_local], padded
#pragma unroll
    for (int p = 0; p < 4; ++p) {
      const int r  = (tid >> 4) + p * 16;  // k-local
      const int c4 = (tid & 15) * 4;       // n-local
      const int k  = k0 + r;
      float4 v;
      if (k < 4096)      v = *(const float4*)&W[(size_t)k * 512 + n0 + c4];
      else if (k < 4104) v = *(const float4*)&bwts[(size_t)(k - 4096) * 512 + n0 + c4];
      else               v = make_float4(0.f, 0.f, 0.f, 0.f);
      Ts[c4 + 0][r] = v.x; Ts[c4 + 1][r] = v.y;
      Ts[c4 + 2][r] = v.z; Ts[c4 + 3][r] = v.w;
    }
    __syncthreads();
    const int nl  = tid >> 2;              // 0..63
    const int kcc = (tid & 3) * 16;        // 0,16,32,48
    u16x8 o0, o1;
#pragma unroll
    for (int q = 0; q < 8; ++q) {
      o0[q] = f2bf(Ts[nl][kcc + q]);
      o1[q] = f2bf(Ts[nl][kcc + 8 + q]);
    }
    unsigned short* dst = Btf + (size_t)(n0 + nl) * KP + k0 + kcc;
    *(u16x8*)dst = o0;
    *(u16x8*)(dst + 8) = o1;
  }
}

// ---------------------------------------------------------------------------
// GEMM: C += A'(2048 x KP) @ Bt^T(KP x 512), bf16 MFMA 16x16x32, fp32 acc.
// 64x64 tile, BK=64, 4 waves (each a 32x32 quadrant), split-K=4 -> 1024 blocks.
// LDS staged via global_load_lds(16B); XOR swizzle (chunk ^= row&7) applied on
// the GLOBAL source address so LDS dst stays wave-uniform-base + lane*16.
// ---------------------------------------------------------------------------
__global__ __launch_bounds__(256, 4) void gemm_kernel(
    const unsigned short* __restrict__ Abf,
    const unsigned short* __restrict__ Btf,
    float* __restrict__ out) {
  const int tid  = threadIdx.x;
  const int kc   = blockIdx.x & (SPLITK - 1);
  const int tile = blockIdx.x >> 2;
  const int nt = tile & 7, mt = tile >> 3;
  const int m0 = mt * 64, n0 = nt * 64;
  const int l = tid & 63, w = tid >> 6;
  const int wm = w >> 1, wn = w & 1;
  const int quad = l >> 4, lr = l & 15;

  __shared__ __align__(16) unsigned short As[64 * 64];
  __shared__ __align__(16) unsigned short Bs[64 * 64];

  f32x4 acc00 = {}, acc01 = {}, acc10 = {}, acc11 = {};

  // staging: thread t -> LDS row sr (64 bf16 = 128B), 16B chunk pc.
  // lane l of wave w writes LDS byte offset w*1024 + l*16 (contiguous). The
  // swizzle permutes WHICH global chunk lands there: lc = pc ^ (sr&7).
  const int sr = tid >> 3, pc = tid & 7;
  const int lc = pc ^ (sr & 7);
  const unsigned short* Ag = Abf + (size_t)(m0 + sr) * KP + lc * 8;
  const unsigned short* Bg = Btf + (size_t)(n0 + sr) * KP + lc * 8;
  unsigned short* AsW = &As[sr * 64 + pc * 8];
  unsigned short* BsW = &Bs[sr * 64 + pc * 8];

  // fragment read offsets (elements); logical chunk (ks*4+quad) lives at
  // physical chunk ((ks*4+quad) ^ (row&7)); row&7 == lr&7 for all i.
  const int sx  = lr & 7;
  const int ar  = (wm * 32 + lr) * 64;
  const int br  = (wn * 32 + lr) * 64;
  const int c0  = ((0 + quad) ^ sx) * 8;   // ks = 0
  const int c1  = ((4 + quad) ^ sx) * 8;   // ks = 1

  int koff = kc * (KSTEPS * 64);
  for (int it = 0; it < KSTEPS; ++it) {
    llds16(Ag + koff,           AsW);
    llds16(Ag + koff + 32 * KP, AsW + 32 * 64);
    llds16(Bg + koff,           BsW);
    llds16(Bg + koff + 32 * KP, BsW + 32 * 64);
    __syncthreads();

    bf16x8 a00 = *(const bf16x8*)&As[ar + c0];
    bf16x8 a10 = *(const bf16x8*)&As[ar + 1024 + c0];
    bf16x8 b00 = *(const bf16x8*)&Bs[br + c0];
    bf16x8 b10 = *(const bf16x8*)&Bs[br + 1024 + c0];
    bf16x8 a01 = *(const bf16x8*)&As[ar + c1];
    bf16x8 a11 = *(const bf16x8*)&As[ar + 1024 + c1];
    bf16x8 b01 = *(const bf16x8*)&Bs[br + c1];
    bf16x8 b11 = *(const bf16x8*)&Bs[br + 1024 + c1];

    acc00 = __builtin_amdgcn_mfma_f32_16x16x32_bf16(a00, b00, acc00, 0, 0, 0);
    acc01 = __builtin_amdgcn_mfma_f32_16x16x32_bf16(a00, b10, acc01, 0, 0, 0);
    acc10 = __builtin_amdgcn_mfma_f32_16x16x32_bf16(a10, b00, acc10, 0, 0, 0);
    acc11 = __builtin_amdgcn_mfma_f32_16x16x32_bf16(a10, b10, acc11, 0, 0, 0);
    acc00 = __builtin_amdgcn_mfma_f32_16x16x32_bf16(a01, b01, acc00, 0, 0, 0);
    acc01 = __builtin_amdgcn_mfma_f32_16x16x32_bf16(a01, b11, acc01, 0, 0, 0);
    acc10 = __builtin_amdgcn_mfma_f32_16x16x32_bf16(a11, b01, acc10, 0, 0, 0);
    acc11 = __builtin_amdgcn_mfma_f32_16x16x32_bf16(a11, b11, acc11, 0, 0, 0);

    __syncthreads();
    koff += 64;
  }

  // C/D layout (verified m89/m91): col = lane&15, row = (lane>>4)*4 + reg
  const int col = n0 + wn * 32 + lr;
  const int row = m0 + wm * 32 + quad * 4;
  float* o00 = out + (size_t)row * OUTDIM + col;
#pragma unroll
  for (int r = 0; r < 4; ++r) {
    unsafeAtomicAdd(o00 + (size_t)r * OUTDIM,             acc00[r]);
    unsafeAtomicAdd(o00 + (size_t)r * OUTDIM + 16,        acc01[r]);
    unsafeAtomicAdd(o00 + (size_t)(16 + r) * OUTDIM,      acc10[r]);
    unsafeAtomicAdd(o00 + (size_t)(16 + r) * OUTDIM + 16, acc11[r]);
  }
}

extern "C" void kernel_launch(void* const* d_in, const int* in_sizes, int n_in,
                              void* d_out, int out_size, void* d_ws, size_t ws_size,
                              hipStream_t stream) {
  const float* inp  = (const float*)d_in[0];   // (2048, 513)
  const float* W    = (const float*)d_in[1];   // (8, 262144) == (4096, 512) row-major
  const float* bwts = (const float*)d_in[2];   // (8, 512)
  float* out = (float*)d_out;

  unsigned short* Abf = (unsigned short*)d_ws;            // 2048*4352 bf16
  unsigned short* Btf = Abf + (size_t)BATCH * KP;         // 512*4352 bf16

  hipMemsetAsync(d_out, 0, (size_t)BATCH * OUTDIM * sizeof(float), stream);
  prep_kernel<<<NBLK_A + NBLK_B, 256, 0, stream>>>(inp, W, bwts, Abf, Btf);
  gemm_kernel<<<(BATCH / 64) * (OUTDIM / 64) * SPLITK, 256, 0, stream>>>(Abf, Btf, out);
}